// Round 9
// baseline (322.763 us; speedup 1.0000x reference)
//
#include <hip/hip_runtime.h>
#include <hip/hip_bf16.h>
#include <cstdint>
#include <cstddef>

typedef short s16x8 __attribute__((ext_vector_type(8)));
typedef float f32x4 __attribute__((ext_vector_type(4)));

#define AVG_LOG_F 2.8332133f  // ln(17)

static __device__ __forceinline__ float b2f(unsigned short u) {
  union { unsigned int i; float f; } x; x.i = ((unsigned int)u) << 16; return x.f;
}
static __device__ __forceinline__ unsigned short f2b(float f) {
  __hip_bfloat16 h = __float2bfloat16(f);
  union { __hip_bfloat16 hh; unsigned short u; } c; c.hh = h; return c.u;
}
static __device__ __forceinline__ unsigned int pack2(float lo, float hi) {
  return (unsigned int)f2b(lo) | ((unsigned int)f2b(hi) << 16);
}
// XOR-swizzled LDS offset for [row][32-short] tiles staged/read as 8-short (16B) chunks.
// slot' = slot ^ ((row>>1)&3): verified r7 -> SQ_LDS_BANK_CONFLICT == 0.
static __device__ __forceinline__ int swz(int row, int slot) {
  return row * 32 + ((slot ^ ((row >> 1) & 3)) << 3);
}

// ---------- h fp32 -> bf16 ----------
__global__ void conv_h_kernel(const float* __restrict__ h, unsigned short* __restrict__ hb, int total4) {
  int i = blockIdx.x * blockDim.x + threadIdx.x;
  if (i >= total4) return;
  const float4 v = ((const float4*)h)[i];
  uint2 r;
  r.x = pack2(v.x, v.y);
  r.y = pack2(v.z, v.w);
  ((uint2*)hb)[i] = r;
}

// ---------- WcatT[c][k] ----------
__global__ void fold_wcat_kernel(const float* __restrict__ W_pre, unsigned short* __restrict__ WcatT) {
  int idx = blockIdx.x * blockDim.x + threadIdx.x;
  int c = idx >> 7, k = idx & 127;
  float v = (c < 128) ? W_pre[k * 128 + c] : W_pre[(128 + k) * 128 + (c - 128)];
  WcatT[c * 128 + k] = f2b(v);
}

// ---------- WfoldT = (W_post @ W_lin)^T ; block 208 computes bfold ----------
__global__ __launch_bounds__(128) void fold_wpost_kernel(
    const float* __restrict__ W_post, const float* __restrict__ b_post,
    const float* __restrict__ W_lin, const float* __restrict__ b_lin,
    unsigned short* __restrict__ WfoldT, float* __restrict__ bfold) {
  __shared__ float wl[128 * 128];
  const int j = threadIdx.x;
  for (int r = 0; r < 128; ++r) wl[r * 128 + j] = W_lin[r * 128 + j];
  __syncthreads();
  if (blockIdx.x == 208) {
    float acc = b_lin[j];
    for (int k = 0; k < 128; ++k) acc += b_post[k] * wl[k * 128 + j];
    bfold[j] = acc;
  } else {
#pragma unroll 2
    for (int ii = 0; ii < 8; ++ii) {
      const int i = blockIdx.x * 8 + ii;
      float acc = 0.f;
      for (int k = 0; k < 128; ++k) acc += W_post[i * 128 + k] * wl[k * 128 + j];
      WfoldT[(size_t)j * 1664 + i] = f2b(acc);
    }
  }
}

// ================= bucketed CSR build =================
__global__ void bucket_hist_kernel(const int* __restrict__ dst, int* __restrict__ bucketCnt, int E) {
  __shared__ int lcnt[256];
  const int tid = threadIdx.x;
  lcnt[tid] = 0;
  __syncthreads();
  for (int e = blockIdx.x * 256 + tid; e < E; e += gridDim.x * 256)
    atomicAdd(&lcnt[dst[e] >> 8], 1);
  __syncthreads();
  if (lcnt[tid] > 0) atomicAdd(&bucketCnt[tid], lcnt[tid]);
}

__global__ void bucket_scan_kernel(const int* __restrict__ bucketCnt, int* __restrict__ bucketBase,
                                   int* __restrict__ bucketCursor, int* __restrict__ rowptr,
                                   int n, int nb, int E) {
  __shared__ int sh[256];
  const int tid = threadIdx.x;
  const int v = (tid < nb) ? bucketCnt[tid] : 0;
  sh[tid] = v;
  __syncthreads();
  for (int o = 1; o < 256; o <<= 1) {
    int t = (tid >= o) ? sh[tid - o] : 0;
    __syncthreads();
    sh[tid] += t;
    __syncthreads();
  }
  const int base = sh[tid] - v;  // exclusive
  if (tid < nb) { bucketBase[tid] = base; bucketCursor[tid] = base; }
  if (tid == nb - 1) bucketBase[nb] = base + v;
  if (tid == 0) rowptr[n] = E;
}

__global__ __launch_bounds__(256) void s1_scatter_kernel(
    const int* __restrict__ src, const int* __restrict__ dst,
    int* __restrict__ bucketCursor, unsigned int* __restrict__ bucketed, int E, int CH) {
  __shared__ int lcnt[256], loff[256], lcur[256], gbase[256];
  __shared__ unsigned int stage[5000];
  __shared__ unsigned char sbid[5000];
  const int tid = threadIdx.x;
  const int c0 = blockIdx.x * CH;
  const int c1 = min(c0 + CH, E);
  const int cnt = c1 - c0;
  if (cnt <= 0) return;
  lcnt[tid] = 0;
  __syncthreads();
  for (int e = c0 + tid; e < c1; e += 256) atomicAdd(&lcnt[dst[e] >> 8], 1);
  __syncthreads();
  const int v = lcnt[tid];
  loff[tid] = 0;
  __syncthreads();
  {
    __shared__ int tmp[256];
    tmp[tid] = v;
    __syncthreads();
    for (int o = 1; o < 256; o <<= 1) {
      int t = (tid >= o) ? tmp[tid - o] : 0;
      __syncthreads();
      tmp[tid] += t;
      __syncthreads();
    }
    loff[tid] = tmp[tid] - v;  // exclusive
  }
  lcur[tid] = loff[tid];
  gbase[tid] = (v > 0) ? atomicAdd(&bucketCursor[tid], v) : 0;
  __syncthreads();
  for (int e = c0 + tid; e < c1; e += 256) {
    const int d = dst[e];
    const int b = d >> 8;
    const int slot = atomicAdd(&lcur[b], 1);
    stage[slot] = ((unsigned int)(d & 255) << 16) | (unsigned int)src[e];
    sbid[slot] = (unsigned char)b;
  }
  __syncthreads();
  for (int i = tid; i < cnt; i += 256) {
    const int b = sbid[i];
    bucketed[gbase[b] + (i - loff[b])] = stage[i];
  }
}

__global__ __launch_bounds__(256) void s2_build_kernel(
    const unsigned int* __restrict__ bucketed, const int* __restrict__ bucketBase,
    int* __restrict__ rowptr, unsigned short* __restrict__ ssrc, int n) {
  __shared__ int ncnt[256], noff[256], ncur[256];
  __shared__ unsigned short csr16[8192];
  const int tid = threadIdx.x;
  const int b = blockIdx.x;
  const int seg0 = bucketBase[b], seg1 = bucketBase[b + 1];
  const int cnt = seg1 - seg0;
  ncnt[tid] = 0;
  __syncthreads();
  for (int i = tid; i < cnt; i += 256) atomicAdd(&ncnt[bucketed[seg0 + i] >> 16], 1);
  __syncthreads();
  const int v = ncnt[tid];
  {
    __shared__ int tmp[256];
    tmp[tid] = v;
    __syncthreads();
    for (int o = 1; o < 256; o <<= 1) {
      int t = (tid >= o) ? tmp[tid - o] : 0;
      __syncthreads();
      tmp[tid] += t;
      __syncthreads();
    }
    noff[tid] = tmp[tid] - v;
  }
  ncur[tid] = noff[tid];
  const int node = (b << 8) + tid;
  if (node < n) rowptr[node] = seg0 + noff[tid];
  __syncthreads();
  for (int i = tid; i < cnt; i += 256) {
    const unsigned int rec = bucketed[seg0 + i];
    const int d = rec >> 16;
    const int slot = atomicAdd(&ncur[d], 1);
    if (slot < 8192) csr16[slot] = (unsigned short)(rec & 0xffffu);
  }
  __syncthreads();
  for (int i = tid; i < cnt; i += 256) ssrc[seg0 + i] = csr16[i];
}

// ---------- GEMM 1: AB[M,256] = hb[M,128] @ WcatT[256,128]^T, bf16 out ----------
__global__ __launch_bounds__(256) void gemm256_kernel(
    const unsigned short* __restrict__ A, const unsigned short* __restrict__ BT,
    unsigned short* __restrict__ outb, int M)
{
  constexpr int LDT = 40;
  constexpr int K = 128, NK = K / 32;
  __shared__ alignas(16) unsigned short Asm[2][128 * LDT];
  __shared__ alignas(16) unsigned short Bsm[2][128 * LDT];
  const int tid = threadIdx.x, lane = tid & 63;
  const int w = tid >> 6, wr = w >> 1, wc = w & 1;
  const int row0 = blockIdx.x * 128;
  const int col0 = blockIdx.y * 128;
  const int srow = tid >> 2, slot = tid & 3;
  const int ar0 = min(row0 + srow, M - 1);
  const int ar1 = min(row0 + srow + 64, M - 1);
  const unsigned short* ap0 = A + (size_t)ar0 * K + slot * 8;
  const unsigned short* ap1 = A + (size_t)ar1 * K + slot * 8;
  const unsigned short* bp0 = BT + (size_t)(col0 + srow) * K + slot * 8;
  const unsigned short* bp1 = BT + (size_t)(col0 + srow + 64) * K + slot * 8;
  const int wa0 = srow * LDT + slot * 8, wa1 = wa0 + 64 * LDT;

  int offA[4], offB[4];
#pragma unroll
  for (int i = 0; i < 4; ++i) {
    offA[i] = (wr * 64 + i * 16 + (lane & 15)) * LDT + (lane >> 4) * 8;
    offB[i] = (wc * 64 + i * 16 + (lane & 15)) * LDT + (lane >> 4) * 8;
  }

  f32x4 acc[4][4] = {};
  uint4 a0 = *(const uint4*)ap0;
  uint4 a1 = *(const uint4*)ap1;
  uint4 b0 = *(const uint4*)bp0;
  uint4 b1 = *(const uint4*)bp1;
  *(uint4*)&Asm[0][wa0] = a0; *(uint4*)&Asm[0][wa1] = a1;
  *(uint4*)&Bsm[0][wa0] = b0; *(uint4*)&Bsm[0][wa1] = b1;
  __syncthreads();

  for (int kt = 0; kt < NK; ++kt) {
    const int cur = kt & 1;
    if (kt + 1 < NK) {
      const int k0 = (kt + 1) * 32;
      a0 = *(const uint4*)(ap0 + k0); a1 = *(const uint4*)(ap1 + k0);
      b0 = *(const uint4*)(bp0 + k0); b1 = *(const uint4*)(bp1 + k0);
    }
    s16x8 af[4], bq[4];
#pragma unroll
    for (int i = 0; i < 4; ++i) af[i] = *(const s16x8*)&Asm[cur][offA[i]];
#pragma unroll
    for (int i = 0; i < 4; ++i) bq[i] = *(const s16x8*)&Bsm[cur][offB[i]];
#pragma unroll
    for (int mi = 0; mi < 4; ++mi)
#pragma unroll
      for (int ni = 0; ni < 4; ++ni)
        acc[mi][ni] = __builtin_amdgcn_mfma_f32_16x16x32_bf16(af[mi], bq[ni], acc[mi][ni], 0, 0, 0);
    if (kt + 1 < NK) {
      const int nxt = cur ^ 1;
      *(uint4*)&Asm[nxt][wa0] = a0; *(uint4*)&Asm[nxt][wa1] = a1;
      *(uint4*)&Bsm[nxt][wa0] = b0; *(uint4*)&Bsm[nxt][wa1] = b1;
      __syncthreads();
    }
  }

#pragma unroll
  for (int mi = 0; mi < 4; ++mi) {
#pragma unroll
    for (int ni = 0; ni < 4; ++ni) {
      const int rbase = row0 + wr * 64 + mi * 16 + (lane >> 4) * 4;
      const int c = col0 + wc * 64 + ni * 16 + (lane & 15);
#pragma unroll
      for (int r = 0; r < 4; ++r) {
        const int rr = rbase + r;
        if (rr < M) outb[(size_t)rr * 256 + c] = f2b(acc[mi][ni][r]);
      }
    }
  }
}

// ---------- per-node aggregation (wave per node, readlane-batched gathers) ----------
#define AGG_EDGE(IDX)                                                                  \
  {                                                                                    \
    const unsigned int v = *(const unsigned int*)(AB + (size_t)(IDX) * 256 + 128 + 2 * lane); \
    const float v0 = b2f((unsigned short)(v & 0xffffu));                               \
    const float v1 = b2f((unsigned short)(v >> 16));                                   \
    s0 += v0; q0 += v0 * v0; mn0 = fminf(mn0, v0); mx0 = fmaxf(mx0, v0);               \
    s1v += v1; q1 += v1 * v1; mn1 = fminf(mn1, v1); mx1 = fmaxf(mx1, v1);              \
  }

__global__ void aggregate_kernel(const unsigned short* __restrict__ AB,
                                 const unsigned short* __restrict__ hb,
                                 const float* __restrict__ b_pre,
                                 const int* __restrict__ rowptr, const unsigned short* __restrict__ ssrc,
                                 unsigned short* __restrict__ Xagg,
                                 float* __restrict__ sc1, float* __restrict__ sc2, int n) {
  const int node = blockIdx.x * 4 + (threadIdx.x >> 6);
  if (node >= n) return;
  const int lane = threadIdx.x & 63;
  const int beg = rowptr[node], end = rowptr[node + 1];
  const int cnt = end - beg;
  float s0 = 0.f, s1v = 0.f, q0 = 0.f, q1 = 0.f;
  float mn0 = 3.4e38f, mn1 = 3.4e38f, mx0 = -3.4e38f, mx1 = -3.4e38f;
  for (int base = beg; base < end; base += 64) {
    const int m = min(64, end - base);
    const int myidx = (base + lane < end) ? (int)ssrc[base + lane] : 0;
    int t = 0;
    for (; t + 8 <= m; t += 8) {
      const int i0 = __builtin_amdgcn_readlane(myidx, t + 0);
      const int i1 = __builtin_amdgcn_readlane(myidx, t + 1);
      const int i2 = __builtin_amdgcn_readlane(myidx, t + 2);
      const int i3 = __builtin_amdgcn_readlane(myidx, t + 3);
      const int i4 = __builtin_amdgcn_readlane(myidx, t + 4);
      const int i5 = __builtin_amdgcn_readlane(myidx, t + 5);
      const int i6 = __builtin_amdgcn_readlane(myidx, t + 6);
      const int i7 = __builtin_amdgcn_readlane(myidx, t + 7);
      AGG_EDGE(i0) AGG_EDGE(i1) AGG_EDGE(i2) AGG_EDGE(i3)
      AGG_EDGE(i4) AGG_EDGE(i5) AGG_EDGE(i6) AGG_EDGE(i7)
    }
    for (; t < m; ++t) {
      const int i0 = __builtin_amdgcn_readlane(myidx, t);
      AGG_EDGE(i0)
    }
  }
  const float degf = (float)(cnt > 0 ? cnt : 1);
  const float2 bp = ((const float2*)b_pre)[lane];
  const unsigned int cpair = *(const unsigned int*)(AB + (size_t)node * 256 + 2 * lane);
  const float c0 = b2f((unsigned short)(cpair & 0xffffu)) + bp.x;
  const float c1 = b2f((unsigned short)(cpair >> 16)) + bp.y;
  float mean0, mean1, std0, std1, lo0, lo1, hi0, hi1;
  if (cnt > 0) {
    const float inv = 1.f / degf;
    const float mu0 = s0 * inv, mu1 = s1v * inv;
    mean0 = c0 + mu0; mean1 = c1 + mu1;
    std0 = sqrtf(fmaxf(q0 * inv - mu0 * mu0, 0.f) + 1e-5f);
    std1 = sqrtf(fmaxf(q1 * inv - mu1 * mu1, 0.f) + 1e-5f);
    lo0 = c0 + mn0; lo1 = c1 + mn1; hi0 = c0 + mx0; hi1 = c1 + mx1;
  } else {
    mean0 = mean1 = lo0 = lo1 = hi0 = hi1 = 0.f;
    std0 = std1 = sqrtf(1e-5f);
  }
  const float logd = logf(degf + 1.f);
  unsigned int* row = (unsigned int*)(Xagg + (size_t)node * 640);
  row[lane]       = *(const unsigned int*)(hb + (size_t)node * 128 + 2 * lane);
  row[64 + lane]  = pack2(mean0, mean1);
  row[128 + lane] = pack2(lo0, lo1);
  row[192 + lane] = pack2(hi0, hi1);
  row[256 + lane] = pack2(std0, std1);
  if (lane == 0) { sc1[node] = logd / AVG_LOG_F; sc2[node] = AVG_LOG_F / logd; }
}

// ---------- GEMM 2: BM=64 tile (782 blocks ~ 3/CU) for latency-chain overlap ----------
// X13 synthesized at staging: kc<640 -> Xagg[kc]; kc<1152 -> s1*Xagg[kc-512]; else s2*Xagg[kc-1024].
static __device__ __forceinline__ uint4 scale8(uint4 r, float s) {
  union { uint4 v; unsigned short h[8]; } in, out;
  in.v = r;
#pragma unroll
  for (int i = 0; i < 8; ++i) out.h[i] = f2b(b2f(in.h[i]) * s);
  return out.v;
}
static __device__ __forceinline__ uint4 loadA_fold(const unsigned short* base, int kc,
                                                   float s1v, float s2v) {
  const bool m1 = kc >= 640;
  const bool m2 = kc >= 1152;
  const int off = kc - (m1 ? 512 : 0) - (m2 ? 512 : 0);
  uint4 r = *(const uint4*)(base + off);
  if (m1) r = scale8(r, m2 ? s2v : s1v);
  return r;
}

__global__ __launch_bounds__(256) void gemm_fold3_kernel(
    const unsigned short* __restrict__ Xagg, const float* __restrict__ sc1,
    const float* __restrict__ sc2, const unsigned short* __restrict__ WT,
    const float* __restrict__ bias, float* __restrict__ out3,
    float* __restrict__ bnsum, int M)
{
  constexpr int NK = 52;  // K = 1664
  __shared__ alignas(16) unsigned short Asm[2][64 * 32];
  __shared__ alignas(16) unsigned short Bsm[2][128 * 32];
  __shared__ float bnacc[256];
  const int tid = threadIdx.x, lane = tid & 63, w = tid >> 6;  // 4 waves, wave tile 64x32
  // bijective XCD-chunked block remap (m204): keeps WfoldT L2-resident per XCD
  const int nwg = gridDim.x, bid = blockIdx.x;
  const int q = nwg >> 3, r8 = nwg & 7;
  const int xcd = bid & 7, off8 = bid >> 3;
  const int blk = (xcd < r8 ? xcd * (q + 1) : r8 * (q + 1) + (xcd - r8) * q) + off8;
  const int row0 = blk * 64;
  const int srow = tid >> 2, slot = tid & 3;  // 64 rows x 4 slots
  const int arow = min(row0 + srow, M - 1);
  const unsigned short* abase = Xagg + (size_t)arow * 640;
  const float s1v = sc1[arow], s2v = sc2[arow];
  const unsigned short* bbase0 = WT + (size_t)srow * 1664 + slot * 8;         // B rows 0..63
  const unsigned short* bbase1 = WT + (size_t)(srow + 64) * 1664 + slot * 8;  // B rows 64..127
  const int wa = swz(srow, slot);
  const int wb0 = swz(srow, slot), wb1 = swz(srow + 64, slot);
  bnacc[tid] = 0.f;

  int offA[4], offB[2];
#pragma unroll
  for (int i = 0; i < 4; ++i) offA[i] = swz(i * 16 + (lane & 15), lane >> 4);
#pragma unroll
  for (int i = 0; i < 2; ++i) offB[i] = swz(w * 32 + i * 16 + (lane & 15), lane >> 4);

  f32x4 acc[4][2] = {};
  uint4 a = loadA_fold(abase, slot * 8, s1v, s2v);
  uint4 b0 = *(const uint4*)bbase0;
  uint4 b1 = *(const uint4*)bbase1;
  *(uint4*)&Asm[0][wa] = a;
  *(uint4*)&Bsm[0][wb0] = b0;
  *(uint4*)&Bsm[0][wb1] = b1;
  __syncthreads();

  for (int kt = 0; kt < NK; ++kt) {
    const int cur = kt & 1;
    const bool pf = kt + 1 < NK;
    if (pf) {
      const int kc = (kt + 1) * 32 + slot * 8;
      a = loadA_fold(abase, kc, s1v, s2v);
      b0 = *(const uint4*)(bbase0 + (kt + 1) * 32);
      b1 = *(const uint4*)(bbase1 + (kt + 1) * 32);
    }
    s16x8 af[4], bq[2];
#pragma unroll
    for (int i = 0; i < 4; ++i) af[i] = *(const s16x8*)&Asm[cur][offA[i]];
#pragma unroll
    for (int i = 0; i < 2; ++i) bq[i] = *(const s16x8*)&Bsm[cur][offB[i]];
#pragma unroll
    for (int mi = 0; mi < 4; ++mi)
#pragma unroll
      for (int ni = 0; ni < 2; ++ni)
        acc[mi][ni] = __builtin_amdgcn_mfma_f32_16x16x32_bf16(af[mi], bq[ni], acc[mi][ni], 0, 0, 0);
    if (pf) {
      const int nxt = cur ^ 1;
      *(uint4*)&Asm[nxt][wa] = a;
      *(uint4*)&Bsm[nxt][wb0] = b0;
      *(uint4*)&Bsm[nxt][wb1] = b1;
      __syncthreads();
    }
  }

  float cs[2] = {0.f, 0.f}, css[2] = {0.f, 0.f};
#pragma unroll
  for (int mi = 0; mi < 4; ++mi) {
#pragma unroll
    for (int ni = 0; ni < 2; ++ni) {
      const int rbase = row0 + mi * 16 + (lane >> 4) * 4;
      const int c = w * 32 + ni * 16 + (lane & 15);
      const float bb = bias[c];
#pragma unroll
      for (int r = 0; r < 4; ++r) {
        const int rr = rbase + r;
        if (rr < M) {
          const float v = acc[mi][ni][r] + bb;
          out3[(size_t)rr * 128 + c] = v;
          cs[ni] += v; css[ni] += v * v;
        }
      }
    }
  }
  __syncthreads();
#pragma unroll
  for (int ni = 0; ni < 2; ++ni) {
    const int c = w * 32 + ni * 16 + (lane & 15);
    atomicAdd(&bnacc[c], cs[ni]);
    atomicAdd(&bnacc[128 + c], css[ni]);
  }
  __syncthreads();
  if (tid < 128) {
    atomicAdd(&bnsum[tid], bnacc[tid]);
    atomicAdd(&bnsum[128 + tid], bnacc[128 + tid]);
  }
}

// ---------- BN finalize ----------
__global__ void bnfinal_kernel(const float* __restrict__ bnsum, const float* __restrict__ gamma,
                               const float* __restrict__ beta, float* __restrict__ sc,
                               float* __restrict__ shv, int n) {
  const int f = threadIdx.x;
  const float inv = 1.f / (float)n;
  const float mu = bnsum[f] * inv;
  const float var = bnsum[128 + f] * inv - mu * mu;
  const float rstd = rsqrtf(var + 1e-5f);
  const float s = gamma[f] * rstd;
  sc[f] = s;
  shv[f] = beta[f] - mu * s;
}

// ---------- BN apply + ReLU + residual ----------
__global__ void epilogue_kernel(const float* __restrict__ out3, const float* __restrict__ h,
                                const float* __restrict__ sc, const float* __restrict__ shv,
                                float* __restrict__ out, int total4) {
  int i = blockIdx.x * blockDim.x + threadIdx.x;
  if (i >= total4) return;
  const int c = (i & 31) * 4;
  const float4 x = ((const float4*)out3)[i];
  const float4 hh = ((const float4*)h)[i];
  float4 r;
  r.x = fmaxf(x.x * sc[c + 0] + shv[c + 0], 0.f) + hh.x;
  r.y = fmaxf(x.y * sc[c + 1] + shv[c + 1], 0.f) + hh.y;
  r.z = fmaxf(x.z * sc[c + 2] + shv[c + 2], 0.f) + hh.z;
  r.w = fmaxf(x.w * sc[c + 3] + shv[c + 3], 0.f) + hh.w;
  ((float4*)out)[i] = r;
}

extern "C" void kernel_launch(void* const* d_in, const int* in_sizes, int n_in,
                              void* d_out, int out_size, void* d_ws, size_t ws_size,
                              hipStream_t stream) {
  const float* h      = (const float*)d_in[0];
  const int*   ei     = (const int*)d_in[1];
  const float* W_pre  = (const float*)d_in[2];
  const float* b_pre  = (const float*)d_in[3];
  const float* W_post = (const float*)d_in[4];
  const float* b_post = (const float*)d_in[5];
  const float* W_lin  = (const float*)d_in[6];
  const float* b_lin  = (const float*)d_in[7];
  const float* gamma  = (const float*)d_in[8];
  const float* beta   = (const float*)d_in[9];

  const int n = in_sizes[0] / 128;
  const int E = in_sizes[1] / 2;
  const int* src = ei;
  const int* dst = ei + E;

  char* ws = (char*)d_ws;
  size_t off = 0;
  auto carve = [&](size_t bytes) {
    off = (off + 255) & ~(size_t)255;
    void* p = ws + off;
    off += bytes;
    return p;
  };
  unsigned short* hb   = (unsigned short*)carve((size_t)n * 128 * 2);
  void* ab_out3        = carve((size_t)n * 256 * 2);  // AB (bf16) then reused as out3 (f32)
  unsigned short* AB   = (unsigned short*)ab_out3;
  float* out3          = (float*)ab_out3;
  unsigned short* Xagg = (unsigned short*)carve((size_t)n * 640 * 2);
  float* sc1           = (float*)carve((size_t)n * 4);
  float* sc2           = (float*)carve((size_t)n * 4);
  unsigned short* WcatT  = (unsigned short*)carve(256 * 128 * 2);
  unsigned short* WfoldT = (unsigned short*)carve((size_t)128 * 1664 * 2);
  float* bfold         = (float*)carve(128 * 4);
  int*   bucketCnt     = (int*)carve(256 * 4);
  int*   bucketBase    = (int*)carve(257 * 4);
  int*   bucketCursor  = (int*)carve(256 * 4);
  unsigned int* bucketed = (unsigned int*)carve((size_t)E * 4);
  int*   rowptr        = (int*)carve((size_t)(n + 1) * 4);
  unsigned short* ssrc = (unsigned short*)carve((size_t)(E + 2) * 2);
  float* bnsum         = (float*)carve(256 * 4);
  float* bnsc          = (float*)carve(128 * 4);
  float* bnsh          = (float*)carve(128 * 4);

  const int total4 = n * 128 / 4;
  const int mt = (n + 127) / 128;
  const int mt64 = (n + 63) / 64;
  const int nb = (n + 255) >> 8;
  const int nS1 = (E + 4999) / 5000;

  conv_h_kernel<<<(total4 + 255) / 256, 256, 0, stream>>>(h, hb, total4);
  fold_wcat_kernel<<<128, 256, 0, stream>>>(W_pre, WcatT);
  fold_wpost_kernel<<<209, 128, 0, stream>>>(W_post, b_post, W_lin, b_lin, WfoldT, bfold);

  hipMemsetAsync(bucketCnt, 0, 256 * 4, stream);
  hipMemsetAsync(bnsum, 0, 256 * 4, stream);
  bucket_hist_kernel<<<256, 256, 0, stream>>>(dst, bucketCnt, E);
  bucket_scan_kernel<<<1, 256, 0, stream>>>(bucketCnt, bucketBase, bucketCursor, rowptr, n, nb, E);
  s1_scatter_kernel<<<nS1, 256, 0, stream>>>(src, dst, bucketCursor, bucketed, E, 5000);
  s2_build_kernel<<<nb, 256, 0, stream>>>(bucketed, bucketBase, rowptr, ssrc, n);

  gemm256_kernel<<<dim3(mt, 2), 256, 0, stream>>>(hb, WcatT, AB, n);
  aggregate_kernel<<<(n + 3) / 4, 256, 0, stream>>>(AB, hb, b_pre, rowptr, ssrc, Xagg, sc1, sc2, n);
  gemm_fold3_kernel<<<mt64, 256, 0, stream>>>(Xagg, sc1, sc2, WfoldT, bfold, out3, bnsum, n);

  bnfinal_kernel<<<1, 128, 0, stream>>>(bnsum, gamma, beta, bnsc, bnsh, n);
  epilogue_kernel<<<(total4 + 255) / 256, 256, 0, stream>>>(out3, h, bnsc, bnsh, (float*)d_out, total4);
}

// Round 10
// 287.004 us; speedup vs baseline: 1.1246x; 1.1246x over previous
//
#include <hip/hip_runtime.h>
#include <hip/hip_bf16.h>
#include <cstdint>
#include <cstddef>

typedef short s16x8 __attribute__((ext_vector_type(8)));
typedef float f32x4 __attribute__((ext_vector_type(4)));

#define AVG_LOG_F 2.8332133f  // ln(17)

static __device__ __forceinline__ float b2f(unsigned short u) {
  union { unsigned int i; float f; } x; x.i = ((unsigned int)u) << 16; return x.f;
}
static __device__ __forceinline__ unsigned short f2b(float f) {
  __hip_bfloat16 h = __float2bfloat16(f);
  union { __hip_bfloat16 hh; unsigned short u; } c; c.hh = h; return c.u;
}
static __device__ __forceinline__ unsigned int pack2(float lo, float hi) {
  return (unsigned int)f2b(lo) | ((unsigned int)f2b(hi) << 16);
}
// convert 8 consecutive f32 -> 8 bf16 packed in uint4
static __device__ __forceinline__ uint4 cvt8(const float* p) {
  const float4 lo = *(const float4*)p;
  const float4 hi = *(const float4*)(p + 4);
  uint4 r;
  r.x = pack2(lo.x, lo.y); r.y = pack2(lo.z, lo.w);
  r.z = pack2(hi.x, hi.y); r.w = pack2(hi.z, hi.w);
  return r;
}
// XOR-swizzled LDS offset for [row][32-short] tiles staged/read as 8-short (16B) chunks.
// slot' = slot ^ ((row>>1)&3): verified r7 -> SQ_LDS_BANK_CONFLICT == 0.
static __device__ __forceinline__ int swz(int row, int slot) {
  return row * 32 + ((slot ^ ((row >> 1) & 3)) << 3);
}

// ---------- WcatT[c][k] ----------
__global__ void fold_wcat_kernel(const float* __restrict__ W_pre, unsigned short* __restrict__ WcatT) {
  int idx = blockIdx.x * blockDim.x + threadIdx.x;
  int c = idx >> 7, k = idx & 127;
  float v = (c < 128) ? W_pre[k * 128 + c] : W_pre[(128 + k) * 128 + (c - 128)];
  WcatT[c * 128 + k] = f2b(v);
}

// ---------- WfoldT = (W_post @ W_lin)^T ; block 208 computes bfold ----------
__global__ __launch_bounds__(128) void fold_wpost_kernel(
    const float* __restrict__ W_post, const float* __restrict__ b_post,
    const float* __restrict__ W_lin, const float* __restrict__ b_lin,
    unsigned short* __restrict__ WfoldT, float* __restrict__ bfold) {
  __shared__ float wl[128 * 128];
  const int j = threadIdx.x;
  for (int r = 0; r < 128; ++r) wl[r * 128 + j] = W_lin[r * 128 + j];
  __syncthreads();
  if (blockIdx.x == 208) {
    float acc = b_lin[j];
    for (int k = 0; k < 128; ++k) acc += b_post[k] * wl[k * 128 + j];
    bfold[j] = acc;
  } else {
#pragma unroll 2
    for (int ii = 0; ii < 8; ++ii) {
      const int i = blockIdx.x * 8 + ii;
      float acc = 0.f;
      for (int k = 0; k < 128; ++k) acc += W_post[i * 128 + k] * wl[k * 128 + j];
      WfoldT[(size_t)j * 1664 + i] = f2b(acc);
    }
  }
}

// ================= bucketed CSR build =================
__global__ void bucket_hist_kernel(const int* __restrict__ dst, int* __restrict__ bucketCnt, int E) {
  __shared__ int lcnt[256];
  const int tid = threadIdx.x;
  lcnt[tid] = 0;
  __syncthreads();
  for (int e = blockIdx.x * 256 + tid; e < E; e += gridDim.x * 256)
    atomicAdd(&lcnt[dst[e] >> 8], 1);
  __syncthreads();
  if (lcnt[tid] > 0) atomicAdd(&bucketCnt[tid], lcnt[tid]);
}

__global__ void bucket_scan_kernel(const int* __restrict__ bucketCnt, int* __restrict__ bucketBase,
                                   int* __restrict__ bucketCursor, int* __restrict__ rowptr,
                                   int n, int nb, int E) {
  __shared__ int sh[256];
  const int tid = threadIdx.x;
  const int v = (tid < nb) ? bucketCnt[tid] : 0;
  sh[tid] = v;
  __syncthreads();
  for (int o = 1; o < 256; o <<= 1) {
    int t = (tid >= o) ? sh[tid - o] : 0;
    __syncthreads();
    sh[tid] += t;
    __syncthreads();
  }
  const int base = sh[tid] - v;  // exclusive
  if (tid < nb) { bucketBase[tid] = base; bucketCursor[tid] = base; }
  if (tid == nb - 1) bucketBase[nb] = base + v;
  if (tid == 0) rowptr[n] = E;
}

__global__ __launch_bounds__(256) void s1_scatter_kernel(
    const int* __restrict__ src, const int* __restrict__ dst,
    int* __restrict__ bucketCursor, unsigned int* __restrict__ bucketed, int E, int CH) {
  __shared__ int lcnt[256], loff[256], lcur[256], gbase[256];
  __shared__ unsigned int stage[5000];
  __shared__ unsigned char sbid[5000];
  const int tid = threadIdx.x;
  const int c0 = blockIdx.x * CH;
  const int c1 = min(c0 + CH, E);
  const int cnt = c1 - c0;
  if (cnt <= 0) return;
  lcnt[tid] = 0;
  __syncthreads();
  for (int e = c0 + tid; e < c1; e += 256) atomicAdd(&lcnt[dst[e] >> 8], 1);
  __syncthreads();
  const int v = lcnt[tid];
  loff[tid] = 0;
  __syncthreads();
  {
    __shared__ int tmp[256];
    tmp[tid] = v;
    __syncthreads();
    for (int o = 1; o < 256; o <<= 1) {
      int t = (tid >= o) ? tmp[tid - o] : 0;
      __syncthreads();
      tmp[tid] += t;
      __syncthreads();
    }
    loff[tid] = tmp[tid] - v;  // exclusive
  }
  lcur[tid] = loff[tid];
  gbase[tid] = (v > 0) ? atomicAdd(&bucketCursor[tid], v) : 0;
  __syncthreads();
  for (int e = c0 + tid; e < c1; e += 256) {
    const int d = dst[e];
    const int b = d >> 8;
    const int slot = atomicAdd(&lcur[b], 1);
    stage[slot] = ((unsigned int)(d & 255) << 16) | (unsigned int)src[e];
    sbid[slot] = (unsigned char)b;
  }
  __syncthreads();
  for (int i = tid; i < cnt; i += 256) {
    const int b = sbid[i];
    bucketed[gbase[b] + (i - loff[b])] = stage[i];
  }
}

__global__ __launch_bounds__(256) void s2_build_kernel(
    const unsigned int* __restrict__ bucketed, const int* __restrict__ bucketBase,
    int* __restrict__ rowptr, unsigned short* __restrict__ ssrc, int n) {
  __shared__ int ncnt[256], noff[256], ncur[256];
  __shared__ unsigned short csr16[8192];
  const int tid = threadIdx.x;
  const int b = blockIdx.x;
  const int seg0 = bucketBase[b], seg1 = bucketBase[b + 1];
  const int cnt = seg1 - seg0;
  ncnt[tid] = 0;
  __syncthreads();
  for (int i = tid; i < cnt; i += 256) atomicAdd(&ncnt[bucketed[seg0 + i] >> 16], 1);
  __syncthreads();
  const int v = ncnt[tid];
  {
    __shared__ int tmp[256];
    tmp[tid] = v;
    __syncthreads();
    for (int o = 1; o < 256; o <<= 1) {
      int t = (tid >= o) ? tmp[tid - o] : 0;
      __syncthreads();
      tmp[tid] += t;
      __syncthreads();
    }
    noff[tid] = tmp[tid] - v;
  }
  ncur[tid] = noff[tid];
  const int node = (b << 8) + tid;
  if (node < n) rowptr[node] = seg0 + noff[tid];
  __syncthreads();
  for (int i = tid; i < cnt; i += 256) {
    const unsigned int rec = bucketed[seg0 + i];
    const int d = rec >> 16;
    const int slot = atomicAdd(&ncur[d], 1);
    if (slot < 8192) csr16[slot] = (unsigned short)(rec & 0xffffu);
  }
  __syncthreads();
  for (int i = tid; i < cnt; i += 256) ssrc[seg0 + i] = csr16[i];
}

// ---------- GEMM 1: AB[M,256] = h(f32)[M,128] @ WcatT[256,128]^T, bf16 out ----------
// A staged directly from f32 h (conv at staging -> conv_h kernel removed)
__global__ __launch_bounds__(256) void gemm256_kernel(
    const float* __restrict__ A, const unsigned short* __restrict__ BT,
    unsigned short* __restrict__ outb, int M)
{
  constexpr int LDT = 40;
  constexpr int K = 128, NK = K / 32;
  __shared__ alignas(16) unsigned short Asm[2][128 * LDT];
  __shared__ alignas(16) unsigned short Bsm[2][128 * LDT];
  const int tid = threadIdx.x, lane = tid & 63;
  const int w = tid >> 6, wr = w >> 1, wc = w & 1;
  const int row0 = blockIdx.x * 128;
  const int col0 = blockIdx.y * 128;
  const int srow = tid >> 2, slot = tid & 3;
  const int ar0 = min(row0 + srow, M - 1);
  const int ar1 = min(row0 + srow + 64, M - 1);
  const float* ap0 = A + (size_t)ar0 * K + slot * 8;
  const float* ap1 = A + (size_t)ar1 * K + slot * 8;
  const unsigned short* bp0 = BT + (size_t)(col0 + srow) * K + slot * 8;
  const unsigned short* bp1 = BT + (size_t)(col0 + srow + 64) * K + slot * 8;
  const int wa0 = srow * LDT + slot * 8, wa1 = wa0 + 64 * LDT;

  int offA[4], offB[4];
#pragma unroll
  for (int i = 0; i < 4; ++i) {
    offA[i] = (wr * 64 + i * 16 + (lane & 15)) * LDT + (lane >> 4) * 8;
    offB[i] = (wc * 64 + i * 16 + (lane & 15)) * LDT + (lane >> 4) * 8;
  }

  f32x4 acc[4][4] = {};
  uint4 a0 = cvt8(ap0);
  uint4 a1 = cvt8(ap1);
  uint4 b0 = *(const uint4*)bp0;
  uint4 b1 = *(const uint4*)bp1;
  *(uint4*)&Asm[0][wa0] = a0; *(uint4*)&Asm[0][wa1] = a1;
  *(uint4*)&Bsm[0][wa0] = b0; *(uint4*)&Bsm[0][wa1] = b1;
  __syncthreads();

  for (int kt = 0; kt < NK; ++kt) {
    const int cur = kt & 1;
    if (kt + 1 < NK) {
      const int k0 = (kt + 1) * 32;
      a0 = cvt8(ap0 + k0); a1 = cvt8(ap1 + k0);
      b0 = *(const uint4*)(bp0 + k0); b1 = *(const uint4*)(bp1 + k0);
    }
    s16x8 af[4], bq[4];
#pragma unroll
    for (int i = 0; i < 4; ++i) af[i] = *(const s16x8*)&Asm[cur][offA[i]];
#pragma unroll
    for (int i = 0; i < 4; ++i) bq[i] = *(const s16x8*)&Bsm[cur][offB[i]];
#pragma unroll
    for (int mi = 0; mi < 4; ++mi)
#pragma unroll
      for (int ni = 0; ni < 4; ++ni)
        acc[mi][ni] = __builtin_amdgcn_mfma_f32_16x16x32_bf16(af[mi], bq[ni], acc[mi][ni], 0, 0, 0);
    if (kt + 1 < NK) {
      const int nxt = cur ^ 1;
      *(uint4*)&Asm[nxt][wa0] = a0; *(uint4*)&Asm[nxt][wa1] = a1;
      *(uint4*)&Bsm[nxt][wa0] = b0; *(uint4*)&Bsm[nxt][wa1] = b1;
      __syncthreads();
    }
  }

#pragma unroll
  for (int mi = 0; mi < 4; ++mi) {
#pragma unroll
    for (int ni = 0; ni < 4; ++ni) {
      const int rbase = row0 + wr * 64 + mi * 16 + (lane >> 4) * 4;
      const int c = col0 + wc * 64 + ni * 16 + (lane & 15);
#pragma unroll
      for (int r = 0; r < 4; ++r) {
        const int rr = rbase + r;
        if (rr < M) outb[(size_t)rr * 256 + c] = f2b(acc[mi][ni][r]);
      }
    }
  }
}

// ---------- per-node aggregation (wave per node, readlane-batched gathers) ----------
#define AGG_EDGE(IDX)                                                                  \
  {                                                                                    \
    const unsigned int v = *(const unsigned int*)(AB + (size_t)(IDX) * 256 + 128 + 2 * lane); \
    const float v0 = b2f((unsigned short)(v & 0xffffu));                               \
    const float v1 = b2f((unsigned short)(v >> 16));                                   \
    s0 += v0; q0 += v0 * v0; mn0 = fminf(mn0, v0); mx0 = fmaxf(mx0, v0);               \
    s1v += v1; q1 += v1 * v1; mn1 = fminf(mn1, v1); mx1 = fmaxf(mx1, v1);              \
  }

__global__ void aggregate_kernel(const unsigned short* __restrict__ AB,
                                 const float* __restrict__ h,
                                 const float* __restrict__ b_pre,
                                 const int* __restrict__ rowptr, const unsigned short* __restrict__ ssrc,
                                 unsigned short* __restrict__ Xagg,
                                 float* __restrict__ sc1, float* __restrict__ sc2, int n) {
  const int node = blockIdx.x * 4 + (threadIdx.x >> 6);
  if (node >= n) return;
  const int lane = threadIdx.x & 63;
  const int beg = rowptr[node], end = rowptr[node + 1];
  const int cnt = end - beg;
  float s0 = 0.f, s1v = 0.f, q0 = 0.f, q1 = 0.f;
  float mn0 = 3.4e38f, mn1 = 3.4e38f, mx0 = -3.4e38f, mx1 = -3.4e38f;
  for (int base = beg; base < end; base += 64) {
    const int m = min(64, end - base);
    const int myidx = (base + lane < end) ? (int)ssrc[base + lane] : 0;
    int t = 0;
    for (; t + 8 <= m; t += 8) {
      const int i0 = __builtin_amdgcn_readlane(myidx, t + 0);
      const int i1 = __builtin_amdgcn_readlane(myidx, t + 1);
      const int i2 = __builtin_amdgcn_readlane(myidx, t + 2);
      const int i3 = __builtin_amdgcn_readlane(myidx, t + 3);
      const int i4 = __builtin_amdgcn_readlane(myidx, t + 4);
      const int i5 = __builtin_amdgcn_readlane(myidx, t + 5);
      const int i6 = __builtin_amdgcn_readlane(myidx, t + 6);
      const int i7 = __builtin_amdgcn_readlane(myidx, t + 7);
      AGG_EDGE(i0) AGG_EDGE(i1) AGG_EDGE(i2) AGG_EDGE(i3)
      AGG_EDGE(i4) AGG_EDGE(i5) AGG_EDGE(i6) AGG_EDGE(i7)
    }
    for (; t < m; ++t) {
      const int i0 = __builtin_amdgcn_readlane(myidx, t);
      AGG_EDGE(i0)
    }
  }
  const float degf = (float)(cnt > 0 ? cnt : 1);
  const float2 bp = ((const float2*)b_pre)[lane];
  const unsigned int cpair = *(const unsigned int*)(AB + (size_t)node * 256 + 2 * lane);
  const float c0 = b2f((unsigned short)(cpair & 0xffffu)) + bp.x;
  const float c1 = b2f((unsigned short)(cpair >> 16)) + bp.y;
  float mean0, mean1, std0, std1, lo0, lo1, hi0, hi1;
  if (cnt > 0) {
    const float inv = 1.f / degf;
    const float mu0 = s0 * inv, mu1 = s1v * inv;
    mean0 = c0 + mu0; mean1 = c1 + mu1;
    std0 = sqrtf(fmaxf(q0 * inv - mu0 * mu0, 0.f) + 1e-5f);
    std1 = sqrtf(fmaxf(q1 * inv - mu1 * mu1, 0.f) + 1e-5f);
    lo0 = c0 + mn0; lo1 = c1 + mn1; hi0 = c0 + mx0; hi1 = c1 + mx1;
  } else {
    mean0 = mean1 = lo0 = lo1 = hi0 = hi1 = 0.f;
    std0 = std1 = sqrtf(1e-5f);
  }
  const float logd = logf(degf + 1.f);
  const float2 hv = ((const float2*)(h + (size_t)node * 128))[lane];
  unsigned int* row = (unsigned int*)(Xagg + (size_t)node * 640);
  row[lane]       = pack2(hv.x, hv.y);
  row[64 + lane]  = pack2(mean0, mean1);
  row[128 + lane] = pack2(lo0, lo1);
  row[192 + lane] = pack2(hi0, hi1);
  row[256 + lane] = pack2(std0, std1);
  if (lane == 0) { sc1[node] = logd / AVG_LOG_F; sc2[node] = AVG_LOG_F / logd; }
}

// ---------- GEMM 2 (unified, BM=128, D=2 prefetch): out3 = X13 @ WfoldT^T + bfold, BN partials fused ----------
static __device__ __forceinline__ uint4 scale8(uint4 r, float s) {
  union { uint4 v; unsigned short h[8]; } in, out;
  in.v = r;
#pragma unroll
  for (int i = 0; i < 8; ++i) out.h[i] = f2b(b2f(in.h[i]) * s);
  return out.v;
}
static __device__ __forceinline__ uint4 loadA_fold(const unsigned short* base, int kc,
                                                   float s1v, float s2v) {
  const bool m1 = kc >= 640;
  const bool m2 = kc >= 1152;
  const int off = kc - (m1 ? 512 : 0) - (m2 ? 512 : 0);
  uint4 r = *(const uint4*)(base + off);
  if (m1) r = scale8(r, m2 ? s2v : s1v);
  return r;
}

#define FOLD_MFMA(CUR)                                                              \
  {                                                                                 \
    s16x8 af[4], bq[2];                                                             \
    _Pragma("unroll") for (int i = 0; i < 4; ++i)                                   \
        af[i] = *(const s16x8*)&Asm[CUR][offA[i]];                                  \
    _Pragma("unroll") for (int i = 0; i < 2; ++i)                                   \
        bq[i] = *(const s16x8*)&Bsm[CUR][offB[i]];                                  \
    _Pragma("unroll") for (int mi = 0; mi < 4; ++mi)                                \
      _Pragma("unroll") for (int ni = 0; ni < 2; ++ni)                              \
        acc[mi][ni] = __builtin_amdgcn_mfma_f32_16x16x32_bf16(af[mi], bq[ni],       \
                                                              acc[mi][ni], 0, 0, 0);\
  }

__global__ __launch_bounds__(512) void gemm_fold2_kernel(
    const unsigned short* __restrict__ Xagg, const float* __restrict__ sc1,
    const float* __restrict__ sc2, const unsigned short* __restrict__ WT,
    const float* __restrict__ bias, float* __restrict__ out3,
    float* __restrict__ bnsum, int M)
{
  constexpr int NK = 52;  // K = 1664, even
  __shared__ alignas(16) unsigned short Asm[2][128 * 32];
  __shared__ alignas(16) unsigned short Bsm[2][128 * 32];
  __shared__ float bnacc[256];
  const int tid = threadIdx.x, lane = tid & 63, w = tid >> 6;
  const int wr = w >> 2, wc = w & 3;  // 2 x 4 waves; wave tile 64 x 32
  const int row0 = blockIdx.x * 128;
  const int srow = tid >> 2, slot = tid & 3;
  const int arow = min(row0 + srow, M - 1);
  const unsigned short* abase = Xagg + (size_t)arow * 640;
  const unsigned short* bbase = WT + (size_t)srow * 1664 + slot * 8;
  const float s1v = sc1[arow], s2v = sc2[arow];
  const int wa = swz(srow, slot);
  if (tid < 256) bnacc[tid] = 0.f;

  int offA[4], offB[2];
#pragma unroll
  for (int i = 0; i < 4; ++i) offA[i] = swz(wr * 64 + i * 16 + (lane & 15), lane >> 4);
#pragma unroll
  for (int i = 0; i < 2; ++i) offB[i] = swz(wc * 32 + i * 16 + (lane & 15), lane >> 4);

  f32x4 acc[4][2] = {};
  // prologue: tile 0 -> LDS[0]; S1 <- tile 1
  {
    uint4 a = loadA_fold(abase, slot * 8, s1v, s2v);
    uint4 b = *(const uint4*)bbase;
    *(uint4*)&Asm[0][wa] = a;
    *(uint4*)&Bsm[0][wa] = b;
  }
  uint4 aS1 = loadA_fold(abase, 32 + slot * 8, s1v, s2v);
  uint4 bS1 = *(const uint4*)(bbase + 32);
  uint4 aS0, bS0;
  __syncthreads();

  for (int kt = 0; kt < NK; kt += 2) {
    // even: issue S0 <- tile kt+2 (2-iter flight); compute LDS[0]=tile kt; write S1(tile kt+1)->LDS[1]
    {
      const int k2 = min(kt + 2, NK - 1) * 32;
      aS0 = loadA_fold(abase, k2 + slot * 8, s1v, s2v);
      bS0 = *(const uint4*)(bbase + k2);
      FOLD_MFMA(0)
      *(uint4*)&Asm[1][wa] = aS1;
      *(uint4*)&Bsm[1][wa] = bS1;
      __syncthreads();
    }
    // odd: issue S1 <- tile kt+3; compute LDS[1]=tile kt+1; write S0(tile kt+2)->LDS[0]
    {
      const int k3 = min(kt + 3, NK - 1) * 32;
      aS1 = loadA_fold(abase, k3 + slot * 8, s1v, s2v);
      bS1 = *(const uint4*)(bbase + k3);
      FOLD_MFMA(1)
      if (kt + 2 < NK) {
        *(uint4*)&Asm[0][wa] = aS0;
        *(uint4*)&Bsm[0][wa] = bS0;
        __syncthreads();
      }
    }
  }

  float cs[2] = {0.f, 0.f}, css[2] = {0.f, 0.f};
#pragma unroll
  for (int mi = 0; mi < 4; ++mi) {
#pragma unroll
    for (int ni = 0; ni < 2; ++ni) {
      const int rbase = row0 + wr * 64 + mi * 16 + (lane >> 4) * 4;
      const int c = wc * 32 + ni * 16 + (lane & 15);
      const float bb = bias[c];
#pragma unroll
      for (int r = 0; r < 4; ++r) {
        const int rr = rbase + r;
        if (rr < M) {
          const float v = acc[mi][ni][r] + bb;
          out3[(size_t)rr * 128 + c] = v;
          cs[ni] += v; css[ni] += v * v;
        }
      }
    }
  }
  __syncthreads();
#pragma unroll
  for (int ni = 0; ni < 2; ++ni) {
    const int c = wc * 32 + ni * 16 + (lane & 15);
    atomicAdd(&bnacc[c], cs[ni]);
    atomicAdd(&bnacc[128 + c], css[ni]);
  }
  __syncthreads();
  if (tid < 128) {
    atomicAdd(&bnsum[tid], bnacc[tid]);
    atomicAdd(&bnsum[128 + tid], bnacc[128 + tid]);
  }
}

// ---------- BN apply (stats finalized inline) + ReLU + residual ----------
__global__ void epilogue_kernel(const float* __restrict__ out3, const float* __restrict__ h,
                                const float* __restrict__ bnsum, const float* __restrict__ gamma,
                                const float* __restrict__ beta, float* __restrict__ out,
                                int n, int total4) {
  int i = blockIdx.x * blockDim.x + threadIdx.x;
  if (i >= total4) return;
  const int c = (i & 31) * 4;
  const float inv = 1.f / (float)n;
  const float4 x = ((const float4*)out3)[i];
  const float4 hh = ((const float4*)h)[i];
  float4 r;
  float* rp = (float*)&r;
  const float* xp = (const float*)&x;
  const float* hp = (const float*)&hh;
#pragma unroll
  for (int j = 0; j < 4; ++j) {
    const int cc = c + j;
    const float mu = bnsum[cc] * inv;
    const float var = bnsum[128 + cc] * inv - mu * mu;
    const float s = gamma[cc] * rsqrtf(var + 1e-5f);
    const float sh = beta[cc] - mu * s;
    rp[j] = fmaxf(xp[j] * s + sh, 0.f) + hp[j];
  }
  ((float4*)out)[i] = r;
}

extern "C" void kernel_launch(void* const* d_in, const int* in_sizes, int n_in,
                              void* d_out, int out_size, void* d_ws, size_t ws_size,
                              hipStream_t stream) {
  const float* h      = (const float*)d_in[0];
  const int*   ei     = (const int*)d_in[1];
  const float* W_pre  = (const float*)d_in[2];
  const float* b_pre  = (const float*)d_in[3];
  const float* W_post = (const float*)d_in[4];
  const float* b_post = (const float*)d_in[5];
  const float* W_lin  = (const float*)d_in[6];
  const float* b_lin  = (const float*)d_in[7];
  const float* gamma  = (const float*)d_in[8];
  const float* beta   = (const float*)d_in[9];

  const int n = in_sizes[0] / 128;
  const int E = in_sizes[1] / 2;
  const int* src = ei;
  const int* dst = ei + E;

  char* ws = (char*)d_ws;
  size_t off = 0;
  auto carve = [&](size_t bytes) {
    off = (off + 255) & ~(size_t)255;
    void* p = ws + off;
    off += bytes;
    return p;
  };
  void* ab_out3        = carve((size_t)n * 256 * 2);  // AB (bf16) then reused as out3 (f32)
  unsigned short* AB   = (unsigned short*)ab_out3;
  float* out3          = (float*)ab_out3;
  unsigned short* Xagg = (unsigned short*)carve((size_t)n * 640 * 2);
  float* sc1           = (float*)carve((size_t)n * 4);
  float* sc2           = (float*)carve((size_t)n * 4);
  unsigned short* WcatT  = (unsigned short*)carve(256 * 128 * 2);
  unsigned short* WfoldT = (unsigned short*)carve((size_t)128 * 1664 * 2);
  float* bfold         = (float*)carve(128 * 4);
  int*   bucketCnt     = (int*)carve(256 * 4);
  int*   bucketBase    = (int*)carve(257 * 4);
  int*   bucketCursor  = (int*)carve(256 * 4);
  unsigned int* bucketed = (unsigned int*)carve((size_t)E * 4);
  int*   rowptr        = (int*)carve((size_t)(n + 1) * 4);
  unsigned short* ssrc = (unsigned short*)carve((size_t)(E + 2) * 2);
  float* bnsum         = (float*)carve(256 * 4);

  const int total4 = n * 128 / 4;
  const int mt = (n + 127) / 128;
  const int nb = (n + 255) >> 8;
  const int nS1 = (E + 4999) / 5000;

  fold_wcat_kernel<<<128, 256, 0, stream>>>(W_pre, WcatT);
  fold_wpost_kernel<<<209, 128, 0, stream>>>(W_post, b_post, W_lin, b_lin, WfoldT, bfold);

  hipMemsetAsync(bucketCnt, 0, 256 * 4, stream);
  hipMemsetAsync(bnsum, 0, 256 * 4, stream);
  bucket_hist_kernel<<<256, 256, 0, stream>>>(dst, bucketCnt, E);
  bucket_scan_kernel<<<1, 256, 0, stream>>>(bucketCnt, bucketBase, bucketCursor, rowptr, n, nb, E);
  s1_scatter_kernel<<<nS1, 256, 0, stream>>>(src, dst, bucketCursor, bucketed, E, 5000);
  s2_build_kernel<<<nb, 256, 0, stream>>>(bucketed, bucketBase, rowptr, ssrc, n);

  gemm256_kernel<<<dim3(mt, 2), 256, 0, stream>>>(h, WcatT, AB, n);
  aggregate_kernel<<<(n + 3) / 4, 256, 0, stream>>>(AB, h, b_pre, rowptr, ssrc, Xagg, sc1, sc2, n);
  gemm_fold2_kernel<<<mt, 512, 0, stream>>>(Xagg, sc1, sc2, WfoldT, bfold, out3, bnsum, n);

  epilogue_kernel<<<(total4 + 255) / 256, 256, 0, stream>>>(out3, h, bnsum, gamma, beta,
                                                            (float*)d_out, n, total4);
}

// Round 11
// 281.723 us; speedup vs baseline: 1.1457x; 1.0187x over previous
//
#include <hip/hip_runtime.h>
#include <hip/hip_bf16.h>
#include <cstdint>
#include <cstddef>

typedef short s16x8 __attribute__((ext_vector_type(8)));
typedef float f32x4 __attribute__((ext_vector_type(4)));

#define AVG_LOG_F 2.8332133f  // ln(17)

static __device__ __forceinline__ float b2f(unsigned short u) {
  union { unsigned int i; float f; } x; x.i = ((unsigned int)u) << 16; return x.f;
}
static __device__ __forceinline__ unsigned short f2b(float f) {
  __hip_bfloat16 h = __float2bfloat16(f);
  union { __hip_bfloat16 hh; unsigned short u; } c; c.hh = h; return c.u;
}
static __device__ __forceinline__ unsigned int pack2(float lo, float hi) {
  return (unsigned int)f2b(lo) | ((unsigned int)f2b(hi) << 16);
}
// convert 8 consecutive f32 -> 8 bf16 packed in uint4
static __device__ __forceinline__ uint4 cvt8(const float* p) {
  const float4 lo = *(const float4*)p;
  const float4 hi = *(const float4*)(p + 4);
  uint4 r;
  r.x = pack2(lo.x, lo.y); r.y = pack2(lo.z, lo.w);
  r.z = pack2(hi.x, hi.y); r.w = pack2(hi.z, hi.w);
  return r;
}
// XOR-swizzled LDS offset for [row][32-short] tiles staged/read as 8-short (16B) chunks.
// slot' = slot ^ ((row>>1)&3): verified r7 -> SQ_LDS_BANK_CONFLICT == 0.
static __device__ __forceinline__ int swz(int row, int slot) {
  return row * 32 + ((slot ^ ((row >> 1) & 3)) << 3);
}

// ---------- WcatT[c][k] ----------
__global__ void fold_wcat_kernel(const float* __restrict__ W_pre, unsigned short* __restrict__ WcatT) {
  int idx = blockIdx.x * blockDim.x + threadIdx.x;
  int c = idx >> 7, k = idx & 127;
  float v = (c < 128) ? W_pre[k * 128 + c] : W_pre[(128 + k) * 128 + (c - 128)];
  WcatT[c * 128 + k] = f2b(v);
}

// ---------- WfoldT = (W_post @ W_lin)^T ; block 208 computes bfold ----------
__global__ __launch_bounds__(128) void fold_wpost_kernel(
    const float* __restrict__ W_post, const float* __restrict__ b_post,
    const float* __restrict__ W_lin, const float* __restrict__ b_lin,
    unsigned short* __restrict__ WfoldT, float* __restrict__ bfold) {
  __shared__ float wl[128 * 128];
  const int j = threadIdx.x;
  for (int r = 0; r < 128; ++r) wl[r * 128 + j] = W_lin[r * 128 + j];
  __syncthreads();
  if (blockIdx.x == 208) {
    float acc = b_lin[j];
    for (int k = 0; k < 128; ++k) acc += b_post[k] * wl[k * 128 + j];
    bfold[j] = acc;
  } else {
#pragma unroll 2
    for (int ii = 0; ii < 8; ++ii) {
      const int i = blockIdx.x * 8 + ii;
      float acc = 0.f;
      for (int k = 0; k < 128; ++k) acc += W_post[i * 128 + k] * wl[k * 128 + j];
      WfoldT[(size_t)j * 1664 + i] = f2b(acc);
    }
  }
}

// ================= bucketed CSR build =================
__global__ void bucket_hist_kernel(const int* __restrict__ dst, int* __restrict__ bucketCnt, int E) {
  __shared__ int lcnt[256];
  const int tid = threadIdx.x;
  lcnt[tid] = 0;
  __syncthreads();
  for (int e = blockIdx.x * 256 + tid; e < E; e += gridDim.x * 256)
    atomicAdd(&lcnt[dst[e] >> 8], 1);
  __syncthreads();
  if (lcnt[tid] > 0) atomicAdd(&bucketCnt[tid], lcnt[tid]);
}

__global__ void bucket_scan_kernel(const int* __restrict__ bucketCnt, int* __restrict__ bucketBase,
                                   int* __restrict__ bucketCursor, int* __restrict__ rowptr,
                                   int n, int nb, int E) {
  __shared__ int sh[256];
  const int tid = threadIdx.x;
  const int v = (tid < nb) ? bucketCnt[tid] : 0;
  sh[tid] = v;
  __syncthreads();
  for (int o = 1; o < 256; o <<= 1) {
    int t = (tid >= o) ? sh[tid - o] : 0;
    __syncthreads();
    sh[tid] += t;
    __syncthreads();
  }
  const int base = sh[tid] - v;  // exclusive
  if (tid < nb) { bucketBase[tid] = base; bucketCursor[tid] = base; }
  if (tid == nb - 1) bucketBase[nb] = base + v;
  if (tid == 0) rowptr[n] = E;
}

__global__ __launch_bounds__(256) void s1_scatter_kernel(
    const int* __restrict__ src, const int* __restrict__ dst,
    int* __restrict__ bucketCursor, unsigned int* __restrict__ bucketed, int E, int CH) {
  __shared__ int lcnt[256], loff[256], lcur[256], gbase[256];
  __shared__ unsigned int stage[5000];
  __shared__ unsigned char sbid[5000];
  const int tid = threadIdx.x;
  const int c0 = blockIdx.x * CH;
  const int c1 = min(c0 + CH, E);
  const int cnt = c1 - c0;
  if (cnt <= 0) return;
  lcnt[tid] = 0;
  __syncthreads();
  for (int e = c0 + tid; e < c1; e += 256) atomicAdd(&lcnt[dst[e] >> 8], 1);
  __syncthreads();
  const int v = lcnt[tid];
  loff[tid] = 0;
  __syncthreads();
  {
    __shared__ int tmp[256];
    tmp[tid] = v;
    __syncthreads();
    for (int o = 1; o < 256; o <<= 1) {
      int t = (tid >= o) ? tmp[tid - o] : 0;
      __syncthreads();
      tmp[tid] += t;
      __syncthreads();
    }
    loff[tid] = tmp[tid] - v;  // exclusive
  }
  lcur[tid] = loff[tid];
  gbase[tid] = (v > 0) ? atomicAdd(&bucketCursor[tid], v) : 0;
  __syncthreads();
  for (int e = c0 + tid; e < c1; e += 256) {
    const int d = dst[e];
    const int b = d >> 8;
    const int slot = atomicAdd(&lcur[b], 1);
    stage[slot] = ((unsigned int)(d & 255) << 16) | (unsigned int)src[e];
    sbid[slot] = (unsigned char)b;
  }
  __syncthreads();
  for (int i = tid; i < cnt; i += 256) {
    const int b = sbid[i];
    bucketed[gbase[b] + (i - loff[b])] = stage[i];
  }
}

__global__ __launch_bounds__(256) void s2_build_kernel(
    const unsigned int* __restrict__ bucketed, const int* __restrict__ bucketBase,
    int* __restrict__ rowptr, unsigned short* __restrict__ ssrc, int n) {
  __shared__ int ncnt[256], noff[256], ncur[256];
  __shared__ unsigned short csr16[8192];
  const int tid = threadIdx.x;
  const int b = blockIdx.x;
  const int seg0 = bucketBase[b], seg1 = bucketBase[b + 1];
  const int cnt = seg1 - seg0;
  ncnt[tid] = 0;
  __syncthreads();
  for (int i = tid; i < cnt; i += 256) atomicAdd(&ncnt[bucketed[seg0 + i] >> 16], 1);
  __syncthreads();
  const int v = ncnt[tid];
  {
    __shared__ int tmp[256];
    tmp[tid] = v;
    __syncthreads();
    for (int o = 1; o < 256; o <<= 1) {
      int t = (tid >= o) ? tmp[tid - o] : 0;
      __syncthreads();
      tmp[tid] += t;
      __syncthreads();
    }
    noff[tid] = tmp[tid] - v;
  }
  ncur[tid] = noff[tid];
  const int node = (b << 8) + tid;
  if (node < n) rowptr[node] = seg0 + noff[tid];
  __syncthreads();
  for (int i = tid; i < cnt; i += 256) {
    const unsigned int rec = bucketed[seg0 + i];
    const int d = rec >> 16;
    const int slot = atomicAdd(&ncur[d], 1);
    if (slot < 8192) csr16[slot] = (unsigned short)(rec & 0xffffu);
  }
  __syncthreads();
  for (int i = tid; i < cnt; i += 256) ssrc[seg0 + i] = csr16[i];
}

// ---------- GEMM 1: AB[M,256] = h(f32)[M,128] @ WcatT[256,128]^T, bf16 out ----------
__global__ __launch_bounds__(256) void gemm256_kernel(
    const float* __restrict__ A, const unsigned short* __restrict__ BT,
    unsigned short* __restrict__ outb, int M)
{
  constexpr int LDT = 40;
  constexpr int K = 128, NK = K / 32;
  __shared__ alignas(16) unsigned short Asm[2][128 * LDT];
  __shared__ alignas(16) unsigned short Bsm[2][128 * LDT];
  const int tid = threadIdx.x, lane = tid & 63;
  const int w = tid >> 6, wr = w >> 1, wc = w & 1;
  const int row0 = blockIdx.x * 128;
  const int col0 = blockIdx.y * 128;
  const int srow = tid >> 2, slot = tid & 3;
  const int ar0 = min(row0 + srow, M - 1);
  const int ar1 = min(row0 + srow + 64, M - 1);
  const float* ap0 = A + (size_t)ar0 * K + slot * 8;
  const float* ap1 = A + (size_t)ar1 * K + slot * 8;
  const unsigned short* bp0 = BT + (size_t)(col0 + srow) * K + slot * 8;
  const unsigned short* bp1 = BT + (size_t)(col0 + srow + 64) * K + slot * 8;
  const int wa0 = srow * LDT + slot * 8, wa1 = wa0 + 64 * LDT;

  int offA[4], offB[4];
#pragma unroll
  for (int i = 0; i < 4; ++i) {
    offA[i] = (wr * 64 + i * 16 + (lane & 15)) * LDT + (lane >> 4) * 8;
    offB[i] = (wc * 64 + i * 16 + (lane & 15)) * LDT + (lane >> 4) * 8;
  }

  f32x4 acc[4][4] = {};
  uint4 a0 = cvt8(ap0);
  uint4 a1 = cvt8(ap1);
  uint4 b0 = *(const uint4*)bp0;
  uint4 b1 = *(const uint4*)bp1;
  *(uint4*)&Asm[0][wa0] = a0; *(uint4*)&Asm[0][wa1] = a1;
  *(uint4*)&Bsm[0][wa0] = b0; *(uint4*)&Bsm[0][wa1] = b1;
  __syncthreads();

  for (int kt = 0; kt < NK; ++kt) {
    const int cur = kt & 1;
    if (kt + 1 < NK) {
      const int k0 = (kt + 1) * 32;
      a0 = cvt8(ap0 + k0); a1 = cvt8(ap1 + k0);
      b0 = *(const uint4*)(bp0 + k0); b1 = *(const uint4*)(bp1 + k0);
    }
    s16x8 af[4], bq[4];
#pragma unroll
    for (int i = 0; i < 4; ++i) af[i] = *(const s16x8*)&Asm[cur][offA[i]];
#pragma unroll
    for (int i = 0; i < 4; ++i) bq[i] = *(const s16x8*)&Bsm[cur][offB[i]];
#pragma unroll
    for (int mi = 0; mi < 4; ++mi)
#pragma unroll
      for (int ni = 0; ni < 4; ++ni)
        acc[mi][ni] = __builtin_amdgcn_mfma_f32_16x16x32_bf16(af[mi], bq[ni], acc[mi][ni], 0, 0, 0);
    if (kt + 1 < NK) {
      const int nxt = cur ^ 1;
      *(uint4*)&Asm[nxt][wa0] = a0; *(uint4*)&Asm[nxt][wa1] = a1;
      *(uint4*)&Bsm[nxt][wa0] = b0; *(uint4*)&Bsm[nxt][wa1] = b1;
      __syncthreads();
    }
  }

#pragma unroll
  for (int mi = 0; mi < 4; ++mi) {
#pragma unroll
    for (int ni = 0; ni < 4; ++ni) {
      const int rbase = row0 + wr * 64 + mi * 16 + (lane >> 4) * 4;
      const int c = col0 + wc * 64 + ni * 16 + (lane & 15);
#pragma unroll
      for (int r = 0; r < 4; ++r) {
        const int rr = rbase + r;
        if (rr < M) outb[(size_t)rr * 256 + c] = f2b(acc[mi][ni][r]);
      }
    }
  }
}

// ---------- per-node aggregation (wave per node, readlane-batched gathers) ----------
#define AGG_EDGE(IDX)                                                                  \
  {                                                                                    \
    const unsigned int v = *(const unsigned int*)(AB + (size_t)(IDX) * 256 + 128 + 2 * lane); \
    const float v0 = b2f((unsigned short)(v & 0xffffu));                               \
    const float v1 = b2f((unsigned short)(v >> 16));                                   \
    s0 += v0; q0 += v0 * v0; mn0 = fminf(mn0, v0); mx0 = fmaxf(mx0, v0);               \
    s1v += v1; q1 += v1 * v1; mn1 = fminf(mn1, v1); mx1 = fmaxf(mx1, v1);              \
  }

__global__ void aggregate_kernel(const unsigned short* __restrict__ AB,
                                 const float* __restrict__ h,
                                 const float* __restrict__ b_pre,
                                 const int* __restrict__ rowptr, const unsigned short* __restrict__ ssrc,
                                 unsigned short* __restrict__ Xagg,
                                 float* __restrict__ sc1, float* __restrict__ sc2, int n) {
  const int node = blockIdx.x * 4 + (threadIdx.x >> 6);
  if (node >= n) return;
  const int lane = threadIdx.x & 63;
  const int beg = rowptr[node], end = rowptr[node + 1];
  const int cnt = end - beg;
  float s0 = 0.f, s1v = 0.f, q0 = 0.f, q1 = 0.f;
  float mn0 = 3.4e38f, mn1 = 3.4e38f, mx0 = -3.4e38f, mx1 = -3.4e38f;
  for (int base = beg; base < end; base += 64) {
    const int m = min(64, end - base);
    const int myidx = (base + lane < end) ? (int)ssrc[base + lane] : 0;
    int t = 0;
    for (; t + 8 <= m; t += 8) {
      const int i0 = __builtin_amdgcn_readlane(myidx, t + 0);
      const int i1 = __builtin_amdgcn_readlane(myidx, t + 1);
      const int i2 = __builtin_amdgcn_readlane(myidx, t + 2);
      const int i3 = __builtin_amdgcn_readlane(myidx, t + 3);
      const int i4 = __builtin_amdgcn_readlane(myidx, t + 4);
      const int i5 = __builtin_amdgcn_readlane(myidx, t + 5);
      const int i6 = __builtin_amdgcn_readlane(myidx, t + 6);
      const int i7 = __builtin_amdgcn_readlane(myidx, t + 7);
      AGG_EDGE(i0) AGG_EDGE(i1) AGG_EDGE(i2) AGG_EDGE(i3)
      AGG_EDGE(i4) AGG_EDGE(i5) AGG_EDGE(i6) AGG_EDGE(i7)
    }
    for (; t < m; ++t) {
      const int i0 = __builtin_amdgcn_readlane(myidx, t);
      AGG_EDGE(i0)
    }
  }
  const float degf = (float)(cnt > 0 ? cnt : 1);
  const float2 bp = ((const float2*)b_pre)[lane];
  const unsigned int cpair = *(const unsigned int*)(AB + (size_t)node * 256 + 2 * lane);
  const float c0 = b2f((unsigned short)(cpair & 0xffffu)) + bp.x;
  const float c1 = b2f((unsigned short)(cpair >> 16)) + bp.y;
  float mean0, mean1, std0, std1, lo0, lo1, hi0, hi1;
  if (cnt > 0) {
    const float inv = 1.f / degf;
    const float mu0 = s0 * inv, mu1 = s1v * inv;
    mean0 = c0 + mu0; mean1 = c1 + mu1;
    std0 = sqrtf(fmaxf(q0 * inv - mu0 * mu0, 0.f) + 1e-5f);
    std1 = sqrtf(fmaxf(q1 * inv - mu1 * mu1, 0.f) + 1e-5f);
    lo0 = c0 + mn0; lo1 = c1 + mn1; hi0 = c0 + mx0; hi1 = c1 + mx1;
  } else {
    mean0 = mean1 = lo0 = lo1 = hi0 = hi1 = 0.f;
    std0 = std1 = sqrtf(1e-5f);
  }
  const float logd = logf(degf + 1.f);
  const float2 hv = ((const float2*)(h + (size_t)node * 128))[lane];
  unsigned int* row = (unsigned int*)(Xagg + (size_t)node * 640);
  row[lane]       = pack2(hv.x, hv.y);
  row[64 + lane]  = pack2(mean0, mean1);
  row[128 + lane] = pack2(lo0, lo1);
  row[192 + lane] = pack2(hi0, hi1);
  row[256 + lane] = pack2(std0, std1);
  if (lane == 0) { sc1[node] = logd / AVG_LOG_F; sc2[node] = AVG_LOG_F / logd; }
}

// ---------- GEMM 2 (unified, BM=128, T4 counted-vmcnt pipeline) ----------
// Raw-prefetch 2 tiles ahead into regs; scale8 deferred to LDS-write time; raw s_barrier
// (lgkm-only drain) keeps the prefetch loads in flight ACROSS barriers (no vmcnt(0) drain).
static __device__ __forceinline__ uint4 scale8(uint4 r, float s) {
  union { uint4 v; unsigned short h[8]; } in, out;
  in.v = r;
#pragma unroll
  for (int i = 0; i < 8; ++i) out.h[i] = f2b(b2f(in.h[i]) * s);
  return out.v;
}
static __device__ __forceinline__ const unsigned short* foldPtr(const unsigned short* base, int kc) {
  return base + kc - (kc >= 640 ? 512 : 0) - (kc >= 1152 ? 512 : 0);
}
static __device__ __forceinline__ uint4 scaleA(uint4 r, int kc, float s1v, float s2v) {
  if (kc >= 1152) return scale8(r, s2v);
  if (kc >= 640)  return scale8(r, s1v);
  return r;
}

#define FOLD_MFMA(CUR)                                                              \
  {                                                                                 \
    s16x8 af[4], bq[2];                                                             \
    _Pragma("unroll") for (int i = 0; i < 4; ++i)                                   \
        af[i] = *(const s16x8*)&Asm[CUR][offA[i]];                                  \
    _Pragma("unroll") for (int i = 0; i < 2; ++i)                                   \
        bq[i] = *(const s16x8*)&Bsm[CUR][offB[i]];                                  \
    _Pragma("unroll") for (int mi = 0; mi < 4; ++mi)                                \
      _Pragma("unroll") for (int ni = 0; ni < 2; ++ni)                              \
        acc[mi][ni] = __builtin_amdgcn_mfma_f32_16x16x32_bf16(af[mi], bq[ni],       \
                                                              acc[mi][ni], 0, 0, 0);\
  }

__global__ __launch_bounds__(512) void gemm_fold2_kernel(
    const unsigned short* __restrict__ Xagg, const float* __restrict__ sc1,
    const float* __restrict__ sc2, const unsigned short* __restrict__ WT,
    const float* __restrict__ bias, float* __restrict__ out3,
    float* __restrict__ bnsum, int M)
{
  constexpr int NK = 52;  // K = 1664, even
  __shared__ alignas(16) unsigned short Asm[2][128 * 32];
  __shared__ alignas(16) unsigned short Bsm[2][128 * 32];
  __shared__ float bnacc[256];
  const int tid = threadIdx.x, lane = tid & 63, w = tid >> 6;
  const int wr = w >> 2, wc = w & 3;  // 2 x 4 waves; wave tile 64 x 32
  const int row0 = blockIdx.x * 128;
  const int srow = tid >> 2, slot = tid & 3;
  const int arow = min(row0 + srow, M - 1);
  const unsigned short* abase = Xagg + (size_t)arow * 640;
  const unsigned short* bbase = WT + (size_t)srow * 1664 + slot * 8;
  const float s1v = sc1[arow], s2v = sc2[arow];
  const int wa = swz(srow, slot);
  if (tid < 256) bnacc[tid] = 0.f;

  int offA[4], offB[2];
#pragma unroll
  for (int i = 0; i < 4; ++i) offA[i] = swz(wr * 64 + i * 16 + (lane & 15), lane >> 4);
#pragma unroll
  for (int i = 0; i < 2; ++i) offB[i] = swz(wc * 32 + i * 16 + (lane & 15), lane >> 4);

  f32x4 acc[4][2] = {};
  // prologue: tile0 -> LDS[0]; raw prefetch tile1 -> P1, tile2 -> P0
  {
    const int kc0 = slot * 8;
    uint4 a = scaleA(*(const uint4*)foldPtr(abase, kc0), kc0, s1v, s2v);
    uint4 b = *(const uint4*)bbase;
    *(uint4*)&Asm[0][wa] = a;
    *(uint4*)&Bsm[0][wa] = b;
  }
  uint4 pa1 = *(const uint4*)foldPtr(abase, 32 + slot * 8);
  uint4 pb1 = *(const uint4*)(bbase + 32);
  uint4 pa0 = *(const uint4*)foldPtr(abase, 64 + slot * 8);
  uint4 pb0 = *(const uint4*)(bbase + 64);
  asm volatile("s_waitcnt lgkmcnt(0)" ::: "memory");
  __builtin_amdgcn_s_barrier();

  for (int kt = 0; kt < NK; kt += 2) {
    {  // even: compute LDS[0]=tile kt; write P1(tile kt+1)->LDS[1]; reissue P1 <- tile kt+3
      const int kcw = (kt + 1) * 32 + slot * 8;
      uint4 aw = scaleA(pa1, kcw, s1v, s2v);  // compiler emits COUNTED vmcnt (P1 is oldest in flight)
      *(uint4*)&Asm[1][wa] = aw;
      *(uint4*)&Bsm[1][wa] = pb1;
      const int kt3 = min(kt + 3, NK - 1);
      pa1 = *(const uint4*)foldPtr(abase, kt3 * 32 + slot * 8);
      pb1 = *(const uint4*)(bbase + kt3 * 32);
      FOLD_MFMA(0)
      asm volatile("s_waitcnt lgkmcnt(0)" ::: "memory");  // LDS writes drained (NOT vmcnt)
      __builtin_amdgcn_s_barrier();
    }
    {  // odd: compute LDS[1]=tile kt+1; write P0(tile kt+2)->LDS[0]; reissue P0 <- tile kt+4
      if (kt + 2 < NK) {
        const int kcw = (kt + 2) * 32 + slot * 8;
        uint4 aw = scaleA(pa0, kcw, s1v, s2v);
        *(uint4*)&Asm[0][wa] = aw;
        *(uint4*)&Bsm[0][wa] = pb0;
        const int kt4 = min(kt + 4, NK - 1);
        pa0 = *(const uint4*)foldPtr(abase, kt4 * 32 + slot * 8);
        pb0 = *(const uint4*)(bbase + kt4 * 32);
        FOLD_MFMA(1)
        asm volatile("s_waitcnt lgkmcnt(0)" ::: "memory");
        __builtin_amdgcn_s_barrier();
      } else {
        FOLD_MFMA(1)  // last tile: no further staging
      }
    }
  }

  float cs[2] = {0.f, 0.f}, css[2] = {0.f, 0.f};
#pragma unroll
  for (int mi = 0; mi < 4; ++mi) {
#pragma unroll
    for (int ni = 0; ni < 2; ++ni) {
      const int rbase = row0 + wr * 64 + mi * 16 + (lane >> 4) * 4;
      const int c = wc * 32 + ni * 16 + (lane & 15);
      const float bb = bias[c];
#pragma unroll
      for (int r = 0; r < 4; ++r) {
        const int rr = rbase + r;
        if (rr < M) {
          const float v = acc[mi][ni][r] + bb;
          out3[(size_t)rr * 128 + c] = v;
          cs[ni] += v; css[ni] += v * v;
        }
      }
    }
  }
  __syncthreads();  // full drain (incl. residual prefetch loads) before bnacc phase
#pragma unroll
  for (int ni = 0; ni < 2; ++ni) {
    const int c = wc * 32 + ni * 16 + (lane & 15);
    atomicAdd(&bnacc[c], cs[ni]);
    atomicAdd(&bnacc[128 + c], css[ni]);
  }
  __syncthreads();
  if (tid < 128) {
    atomicAdd(&bnsum[tid], bnacc[tid]);
    atomicAdd(&bnsum[128 + tid], bnacc[128 + tid]);
  }
}

// ---------- BN apply (stats finalized inline) + ReLU + residual ----------
__global__ void epilogue_kernel(const float* __restrict__ out3, const float* __restrict__ h,
                                const float* __restrict__ bnsum, const float* __restrict__ gamma,
                                const float* __restrict__ beta, float* __restrict__ out,
                                int n, int total4) {
  int i = blockIdx.x * blockDim.x + threadIdx.x;
  if (i >= total4) return;
  const int c = (i & 31) * 4;
  const float inv = 1.f / (float)n;
  const float4 x = ((const float4*)out3)[i];
  const float4 hh = ((const float4*)h)[i];
  float4 r;
  float* rp = (float*)&r;
  const float* xp = (const float*)&x;
  const float* hp = (const float*)&hh;
#pragma unroll
  for (int j = 0; j < 4; ++j) {
    const int cc = c + j;
    const float mu = bnsum[cc] * inv;
    const float var = bnsum[128 + cc] * inv - mu * mu;
    const float s = gamma[cc] * rsqrtf(var + 1e-5f);
    const float sh = beta[cc] - mu * s;
    rp[j] = fmaxf(xp[j] * s + sh, 0.f) + hp[j];
  }
  ((float4*)out)[i] = r;
}

extern "C" void kernel_launch(void* const* d_in, const int* in_sizes, int n_in,
                              void* d_out, int out_size, void* d_ws, size_t ws_size,
                              hipStream_t stream) {
  const float* h      = (const float*)d_in[0];
  const int*   ei     = (const int*)d_in[1];
  const float* W_pre  = (const float*)d_in[2];
  const float* b_pre  = (const float*)d_in[3];
  const float* W_post = (const float*)d_in[4];
  const float* b_post = (const float*)d_in[5];
  const float* W_lin  = (const float*)d_in[6];
  const float* b_lin  = (const float*)d_in[7];
  const float* gamma  = (const float*)d_in[8];
  const float* beta   = (const float*)d_in[9];

  const int n = in_sizes[0] / 128;
  const int E = in_sizes[1] / 2;
  const int* src = ei;
  const int* dst = ei + E;

  char* ws = (char*)d_ws;
  size_t off = 0;
  auto carve = [&](size_t bytes) {
    off = (off + 255) & ~(size_t)255;
    void* p = ws + off;
    off += bytes;
    return p;
  };
  void* ab_out3        = carve((size_t)n * 256 * 2);  // AB (bf16) then reused as out3 (f32)
  unsigned short* AB   = (unsigned short*)ab_out3;
  float* out3          = (float*)ab_out3;
  unsigned short* Xagg = (unsigned short*)carve((size_t)n * 640 * 2);
  float* sc1           = (float*)carve((size_t)n * 4);
  float* sc2           = (float*)carve((size_t)n * 4);
  unsigned short* WcatT  = (unsigned short*)carve(256 * 128 * 2);
  unsigned short* WfoldT = (unsigned short*)carve((size_t)128 * 1664 * 2);
  float* bfold         = (float*)carve(128 * 4);
  int*   bucketCnt     = (int*)carve(256 * 4);
  int*   bucketBase    = (int*)carve(257 * 4);
  int*   bucketCursor  = (int*)carve(256 * 4);
  unsigned int* bucketed = (unsigned int*)carve((size_t)E * 4);
  int*   rowptr        = (int*)carve((size_t)(n + 1) * 4);
  unsigned short* ssrc = (unsigned short*)carve((size_t)(E + 2) * 2);
  float* bnsum         = (float*)carve(256 * 4);

  const int total4 = n * 128 / 4;
  const int mt = (n + 127) / 128;
  const int nb = (n + 255) >> 8;
  const int nS1 = (E + 4999) / 5000;

  fold_wcat_kernel<<<128, 256, 0, stream>>>(W_pre, WcatT);
  fold_wpost_kernel<<<209, 128, 0, stream>>>(W_post, b_post, W_lin, b_lin, WfoldT, bfold);

  hipMemsetAsync(bucketCnt, 0, 256 * 4, stream);
  hipMemsetAsync(bnsum, 0, 256 * 4, stream);
  bucket_hist_kernel<<<256, 256, 0, stream>>>(dst, bucketCnt, E);
  bucket_scan_kernel<<<1, 256, 0, stream>>>(bucketCnt, bucketBase, bucketCursor, rowptr, n, nb, E);
  s1_scatter_kernel<<<nS1, 256, 0, stream>>>(src, dst, bucketCursor, bucketed, E, 5000);
  s2_build_kernel<<<nb, 256, 0, stream>>>(bucketed, bucketBase, rowptr, ssrc, n);

  gemm256_kernel<<<dim3(mt, 2), 256, 0, stream>>>(h, WcatT, AB, n);
  aggregate_kernel<<<(n + 3) / 4, 256, 0, stream>>>(AB, h, b_pre, rowptr, ssrc, Xagg, sc1, sc2, n);
  gemm_fold2_kernel<<<mt, 512, 0, stream>>>(Xagg, sc1, sc2, WfoldT, bfold, out3, bnsum, n);

  epilogue_kernel<<<(total4 + 255) / 256, 256, 0, stream>>>(out3, h, bnsum, gamma, beta,
                                                            (float*)d_out, n, total4);
}